// Round 13
// baseline (34.445 us; speedup 1.0000x reference)
//
#include <hip/hip_runtime.h>

#define G 7
#define CCH 256
#define NLVL 6

__device__ __constant__ int kD[NLVL]  = {38, 19, 10, 5, 3, 1};
__device__ __constant__ int kD2[NLVL] = {1444, 361, 100, 25, 9, 1};
// base offset (in floats) of each level inside the transposed fmap buffer
__device__ __constant__ int kBaseT[NLVL + 1] = {0, 369664, 462080, 487680, 494080, 496384, 496640};

#define FMT_TOTAL 496640  // floats

// ---------------- kernel 1: transpose fmaps [C][D*D] -> [D*D][C] ----------------
__global__ __launch_bounds__(256) void transpose_fmaps(
    const float* __restrict__ f0, const float* __restrict__ f1,
    const float* __restrict__ f2, const float* __restrict__ f3,
    const float* __restrict__ f4, const float* __restrict__ f5,
    float* __restrict__ fmT)
{
    int o = blockIdx.x * blockDim.x + threadIdx.x;
    if (o >= FMT_TOTAL) return;
    int l = 0;
#pragma unroll
    for (int k = 1; k < NLVL; ++k) l += (o >= kBaseT[k]);
    int rel = o - kBaseT[l];
    int p = rel >> 8;        // position within D*D
    int c = rel & 255;       // channel
    const float* f;
    switch (l) {
        case 0: f = f0; break;
        case 1: f = f1; break;
        case 2: f = f2; break;
        case 3: f = f3; break;
        case 4: f = f4; break;
        default: f = f5; break;
    }
    fmT[o] = f[c * kD2[l] + p];
}

// ---------------- kernel 2: one block per box; separable hoisted params ----------------
__global__ __launch_bounds__(256) void roialign_main(
    const float* __restrict__ boxes, const float* __restrict__ fmT,
    float* __restrict__ out)
{
    __shared__ float sOut[CCH * 49];   // [c][g]; wave w owns rows 64w..64w+63

    int n = blockIdx.x;
    int tid = threadIdx.x;             // == channel c

    // box params (wave-uniform; all lanes compute redundantly)
    float bx1 = boxes[n * 4 + 0];
    float by1 = boxes[n * 4 + 1];
    float bx2 = boxes[n * 4 + 2];
    float by2 = boxes[n * 4 + 3];
    float w = bx2 - bx1;
    float h = by2 - by1;
    // level: clip(floor(5 + log2(sqrt(w*h))), 0, 5), same f32 op order as ref
    float avg = sqrtf(w * h);
    float lf = floorf((float)(NLVL - 1) + log2f(avg));
    lf = fminf(fmaxf(lf, 0.0f), (float)(NLVL - 1));
    int lvl = __builtin_amdgcn_readfirstlane((int)lf);   // scalarize
    int D    = kD[lvl];
    int base = kBaseT[lvl];
    float Dm1 = (float)(D - 1);
    int Dm1i = D - 1;
    int Drow = D << 8;                 // D * CCH (floats)

    // ---- hoisted separable tables in registers (static indices only) ----
    float xpA[7], xpB[7], ypA[7], ypB[7];
    int   xoA[7], xoB[7], yoA[7], yoB[7];
#pragma unroll
    for (int i = 0; i < 7; ++i) {
        // exact reference op order: clip(x1 + i*(x2-x1)/6, 0, 1)
        float xr = fminf(fmaxf(bx1 + ((float)i * w) / 6.0f, 0.0f), 1.0f);
        float ux = xr * Dm1;
        float xf = floorf(ux);
        float fx = ux - xf;            // px1
        int ix0 = (int)xf;
        int o0 = ix0 * Drow;
        xpA[i] = 1.0f - fx;
        xpB[i] = fx;
        xoA[i] = o0;
        xoB[i] = o0 + ((ix0 < Dm1i) ? Drow : 0);

        float yr = fminf(fmaxf(by1 + ((float)i * h) / 6.0f, 0.0f), 1.0f);
        float uy = yr * Dm1;
        float yf = floorf(uy);
        float fy = uy - yf;            // py1
        int iy0 = (int)yf;
        int p0 = iy0 << 8;             // iy0 * CCH
        ypA[i] = 1.0f - fy;
        ypB[i] = fy;
        yoA[i] = p0;
        yoB[i] = p0 + ((iy0 < Dm1i) ? 256 : 0);
    }

    int bt = base + tid;               // fold channel into cell offset
    float* row = sOut + tid * 49;      // bank = (49*tid)%32: permutation, conflict-free

    // ---- gather/FMA: per-g = 2-add addr combine + 4 loads + 6 FMA-class ----
#pragma unroll
    for (int g = 0; g < 49; ++g) {
        const int i = g / 7;
        const int j = g - 7 * i;
        int oxa = bt + xoA[i];         // CSE'd across the 7 j's of this i
        int oxb = bt + xoB[i];
        float a00 = fmT[oxa + yoA[j]];
        float a10 = fmT[oxb + yoA[j]];
        float a01 = fmT[oxa + yoB[j]];
        float a11 = fmT[oxb + yoB[j]];
        float vx0 = xpA[i] * a00 + xpB[i] * a10;   // x-interp at y0
        float vx1 = xpA[i] * a01 + xpB[i] * a11;   // x-interp at y1
        row[g] = ypA[j] * vx0 + ypB[j] * vx1;
    }

    // wave-local DS ordering: readback below reads rows written by lanes of THIS
    // wave only (cross-lane, same wave). Compiler can't see the cross-lane dep;
    // explicit wait + scheduling fence required (rule #18).
    asm volatile("s_waitcnt lgkmcnt(0)" ::: "memory");
    __builtin_amdgcn_sched_barrier(0);

    // ---- writeback: wave streams its 64-channel slab (784 float4, coalesced) ----
    int wv_id = tid >> 6;
    int lane = tid & 63;
    const float4* s4 = (const float4*)sOut + wv_id * 784;
    float4* out4 = (float4*)(out + (size_t)n * (CCH * G * G)) + wv_id * 784;
#pragma unroll
    for (int k = 0; k < 12; ++k) {
        out4[k * 64 + lane] = s4[k * 64 + lane];
    }
    if (lane < 16) out4[768 + lane] = s4[768 + lane];   // 784 = 12*64 + 16
}

// ---------------- fallback (round-2 kernel) if ws too small ----------------
__global__ __launch_bounds__(256) void roialign_fallback(
    const float* __restrict__ boxes,
    const float* __restrict__ f0, const float* __restrict__ f1,
    const float* __restrict__ f2, const float* __restrict__ f3,
    const float* __restrict__ f4, const float* __restrict__ f5,
    float* __restrict__ out, int total4)
{
    int t = blockIdx.x * blockDim.x + threadIdx.x;
    if (t >= total4) return;
    const int perN = CCH * G * G;
    int idx = t * 4;
    int n = idx / perN;
    int rem = idx - n * perN;
    float bx1 = boxes[n * 4 + 0], by1 = boxes[n * 4 + 1];
    float bx2 = boxes[n * 4 + 2], by2 = boxes[n * 4 + 3];
    float w = bx2 - bx1, h = by2 - by1;
    float avg = sqrtf(w * h);
    float lf = floorf((float)(NLVL - 1) + log2f(avg));
    lf = fminf(fmaxf(lf, 0.0f), (float)(NLVL - 1));
    int lvl = (int)lf;
    const float* fm;
    switch (lvl) {
        case 0: fm = f0; break;
        case 1: fm = f1; break;
        case 2: fm = f2; break;
        case 3: fm = f3; break;
        case 4: fm = f4; break;
        default: fm = f5; break;
    }
    int D = kD[lvl];
    float Dm1 = (float)(D - 1);
    float4 res;
    float* rp = &res.x;
#pragma unroll
    for (int k = 0; k < 4; ++k) {
        int e = rem + k;
        int j = e % G;
        int iq = e / G;
        int i = iq % G;
        int c = iq / G;
        float xr = fminf(fmaxf(bx1 + ((float)i * w) / 6.0f, 0.0f), 1.0f);
        float yr = fminf(fmaxf(by1 + ((float)j * h) / 6.0f, 0.0f), 1.0f);
        float ux = xr * Dm1, uy = yr * Dm1;
        float x0 = floorf(ux), y0 = floorf(uy);
        int ix0 = (int)x0, iy0 = (int)y0;
        float fx = ux - x0, fy = uy - y0;
        int ix1 = min(ix0 + 1, D - 1), iy1 = min(iy0 + 1, D - 1);
        const float* p = fm + c * D * D;
        float v00 = p[ix0 * D + iy0], v10 = p[ix1 * D + iy0];
        float v01 = p[ix0 * D + iy1], v11 = p[ix1 * D + iy1];
        float px0 = 1.0f - fx, py0 = 1.0f - fy;
        rp[k] = px0 * py0 * v00 + fx * py0 * v10 + px0 * fy * v01 + fx * fy * v11;
    }
    reinterpret_cast<float4*>(out)[t] = res;
}

extern "C" void kernel_launch(void* const* d_in, const int* in_sizes, int n_in,
                              void* d_out, int out_size, void* d_ws, size_t ws_size,
                              hipStream_t stream) {
    const float* boxes = (const float*)d_in[0];
    const float* f0 = (const float*)d_in[1];
    const float* f1 = (const float*)d_in[2];
    const float* f2 = (const float*)d_in[3];
    const float* f3 = (const float*)d_in[4];
    const float* f4 = (const float*)d_in[5];
    const float* f5 = (const float*)d_in[6];
    float* out = (float*)d_out;
    int N = in_sizes[0] / 4;

    if (ws_size >= (size_t)FMT_TOTAL * sizeof(float)) {
        float* fmT = (float*)d_ws;
        transpose_fmaps<<<(FMT_TOTAL + 255) / 256, 256, 0, stream>>>(
            f0, f1, f2, f3, f4, f5, fmT);
        roialign_main<<<N, 256, 0, stream>>>(boxes, fmT, out);
    } else {
        int total4 = out_size / 4;
        roialign_fallback<<<(total4 + 255) / 256, 256, 0, stream>>>(
            boxes, f0, f1, f2, f3, f4, f5, out, total4);
    }
}

// Round 14
// 32.512 us; speedup vs baseline: 1.0595x; 1.0595x over previous
//
#include <hip/hip_runtime.h>

#define G 7
#define CCH 256
#define NLVL 6

__device__ __constant__ int kD[NLVL]  = {38, 19, 10, 5, 3, 1};
__device__ __constant__ int kD2[NLVL] = {1444, 361, 100, 25, 9, 1};
// base offset (in floats) of each level inside the transposed fmap buffer
__device__ __constant__ int kBaseT[NLVL + 1] = {0, 369664, 462080, 487680, 494080, 496384, 496640};

#define FMT_TOTAL 496640  // floats

// readlane a float via bit_cast (readlane builtin is i32)
#define RL_F(v, l) __builtin_bit_cast(float, __builtin_amdgcn_readlane(__builtin_bit_cast(int, (v)), (l)))
#define RL_I(v, l) __builtin_amdgcn_readlane((v), (l))

// ---------------- kernel 1: transpose fmaps [C][D*D] -> [D*D][C] ----------------
__global__ __launch_bounds__(256) void transpose_fmaps(
    const float* __restrict__ f0, const float* __restrict__ f1,
    const float* __restrict__ f2, const float* __restrict__ f3,
    const float* __restrict__ f4, const float* __restrict__ f5,
    float* __restrict__ fmT)
{
    int o = blockIdx.x * blockDim.x + threadIdx.x;
    if (o >= FMT_TOTAL) return;
    int l = 0;
#pragma unroll
    for (int k = 1; k < NLVL; ++k) l += (o >= kBaseT[k]);
    int rel = o - kBaseT[l];
    int p = rel >> 8;        // position within D*D
    int c = rel & 255;       // channel
    const float* f;
    switch (l) {
        case 0: f = f0; break;
        case 1: f = f1; break;
        case 2: f = f2; break;
        case 3: f = f3; break;
        case 4: f = f4; break;
        default: f = f5; break;
    }
    fmT[o] = f[c * kD2[l] + p];
}

// ---------------- kernel 2: one block per box; uniform work in SGPRs ----------------
__global__ __launch_bounds__(256) void roialign_main(
    const float* __restrict__ boxes, const float* __restrict__ fmT,
    float* __restrict__ out)
{
    __shared__ float sOut[CCH * 49];   // [c][g]; wave w owns rows 64w..64w+63

    int n = blockIdx.x;
    int tid = threadIdx.x;             // == channel c
    int lane = tid & 63;

    // box params (uniform; boxes+4n is block-uniform -> scalar loads)
    float bx1 = boxes[n * 4 + 0];
    float by1 = boxes[n * 4 + 1];
    float bx2 = boxes[n * 4 + 2];
    float by2 = boxes[n * 4 + 3];
    float w = bx2 - bx1;
    float h = by2 - by1;
    // level: clip(floor(5 + log2(sqrt(w*h))), 0, 5), same f32 op order as ref
    float avg = sqrtf(w * h);
    float lf = floorf((float)(NLVL - 1) + log2f(avg));
    lf = fminf(fmaxf(lf, 0.0f), (float)(NLVL - 1));
    int lvl = __builtin_amdgcn_readfirstlane((int)lf);   // scalarize
    int D    = kD[lvl];
    int base = kBaseT[lvl];
    float Dm1 = (float)(D - 1);
    int Dm1i = D - 1;
    int Drow = D << 8;                 // D * CCH (floats)

    // ---- lane-parallel separable params: lane t computes the t-th i/j params ----
    // (valid for lane<7; other lanes compute clipped garbage, never read)
    float t = (float)lane;
    // exact reference op order: clip(x1 + t*(x2-x1)/6, 0, 1)
    float xr = fminf(fmaxf(bx1 + (t * w) / 6.0f, 0.0f), 1.0f);
    float ux = xr * Dm1;
    float xf = floorf(ux);
    float fxv = ux - xf;               // px1
    int ix0 = (int)xf;
    int xoAv = ix0 * Drow;
    int xoBv = xoAv + ((ix0 < Dm1i) ? Drow : 0);
    float xpAv = 1.0f - fxv;           // px0

    float yr = fminf(fmaxf(by1 + (t * h) / 6.0f, 0.0f), 1.0f);
    float uy = yr * Dm1;
    float yf = floorf(uy);
    float fyv = uy - yf;               // py1
    int iy0 = (int)yf;
    int yoAv = iy0 << 8;               // iy0 * CCH
    int yoBv = yoAv + ((iy0 < Dm1i) ? 256 : 0);
    float ypAv = 1.0f - fyv;           // py0

    float* row = sOut + tid * 49;      // bank = (49*tid)%32: permutation, conflict-free

    // ---- gather/FMA: per-g uniform offsets in SGPRs, loads via saddr+tid ----
#pragma unroll
    for (int i = 0; i < 7; ++i) {
        float sxA = RL_F(xpAv, i);     // SGPR weights
        float sxB = RL_F(fxv, i);
        int   uxa = base + RL_I(xoAv, i);   // uniform (SALU)
        int   uxb = base + RL_I(xoBv, i);
#pragma unroll
        for (int j = 0; j < 7; ++j) {
            float syA = RL_F(ypAv, j);
            float syB = RL_F(fyv, j);
            int uyA = RL_I(yoAv, j);
            int uyB = RL_I(yoBv, j);
            // uniform base + divergent tid -> global_load_dword v, v_tid, s[saddr]
            float a00 = fmT[(uxa + uyA) + tid];
            float a10 = fmT[(uxb + uyA) + tid];
            float a01 = fmT[(uxa + uyB) + tid];
            float a11 = fmT[(uxb + uyB) + tid];
            float vx0 = sxA * a00 + sxB * a10;   // x-interp at y0
            float vx1 = sxA * a01 + sxB * a11;   // x-interp at y1
            row[i * 7 + j] = syA * vx0 + syB * vx1;
        }
    }

    // wave-local DS ordering: readback below reads rows written by lanes of THIS
    // wave only (cross-lane, same wave). Compiler can't see the cross-lane dep;
    // explicit wait + scheduling fence required (rule #18).
    asm volatile("s_waitcnt lgkmcnt(0)" ::: "memory");
    __builtin_amdgcn_sched_barrier(0);

    // ---- writeback: wave streams its 64-channel slab (784 float4, coalesced) ----
    int wv_id = tid >> 6;
    const float4* s4 = (const float4*)sOut + wv_id * 784;
    float4* out4 = (float4*)(out + (size_t)n * (CCH * G * G)) + wv_id * 784;
#pragma unroll
    for (int k = 0; k < 12; ++k) {
        out4[k * 64 + lane] = s4[k * 64 + lane];
    }
    if (lane < 16) out4[768 + lane] = s4[768 + lane];   // 784 = 12*64 + 16
}

// ---------------- fallback (round-2 kernel) if ws too small ----------------
__global__ __launch_bounds__(256) void roialign_fallback(
    const float* __restrict__ boxes,
    const float* __restrict__ f0, const float* __restrict__ f1,
    const float* __restrict__ f2, const float* __restrict__ f3,
    const float* __restrict__ f4, const float* __restrict__ f5,
    float* __restrict__ out, int total4)
{
    int t = blockIdx.x * blockDim.x + threadIdx.x;
    if (t >= total4) return;
    const int perN = CCH * G * G;
    int idx = t * 4;
    int n = idx / perN;
    int rem = idx - n * perN;
    float bx1 = boxes[n * 4 + 0], by1 = boxes[n * 4 + 1];
    float bx2 = boxes[n * 4 + 2], by2 = boxes[n * 4 + 3];
    float w = bx2 - bx1, h = by2 - by1;
    float avg = sqrtf(w * h);
    float lf = floorf((float)(NLVL - 1) + log2f(avg));
    lf = fminf(fmaxf(lf, 0.0f), (float)(NLVL - 1));
    int lvl = (int)lf;
    const float* fm;
    switch (lvl) {
        case 0: fm = f0; break;
        case 1: fm = f1; break;
        case 2: fm = f2; break;
        case 3: fm = f3; break;
        case 4: fm = f4; break;
        default: fm = f5; break;
    }
    int D = kD[lvl];
    float Dm1 = (float)(D - 1);
    float4 res;
    float* rp = &res.x;
#pragma unroll
    for (int k = 0; k < 4; ++k) {
        int e = rem + k;
        int j = e % G;
        int iq = e / G;
        int i = iq % G;
        int c = iq / G;
        float xr = fminf(fmaxf(bx1 + ((float)i * w) / 6.0f, 0.0f), 1.0f);
        float yr = fminf(fmaxf(by1 + ((float)j * h) / 6.0f, 0.0f), 1.0f);
        float ux = xr * Dm1, uy = yr * Dm1;
        float x0 = floorf(ux), y0 = floorf(uy);
        int ix0 = (int)x0, iy0 = (int)y0;
        float fx = ux - x0, fy = uy - y0;
        int ix1 = min(ix0 + 1, D - 1), iy1 = min(iy0 + 1, D - 1);
        const float* p = fm + c * D * D;
        float v00 = p[ix0 * D + iy0], v10 = p[ix1 * D + iy0];
        float v01 = p[ix0 * D + iy1], v11 = p[ix1 * D + iy1];
        float px0 = 1.0f - fx, py0 = 1.0f - fy;
        rp[k] = px0 * py0 * v00 + fx * py0 * v10 + px0 * fy * v01 + fx * fy * v11;
    }
    reinterpret_cast<float4*>(out)[t] = res;
}

extern "C" void kernel_launch(void* const* d_in, const int* in_sizes, int n_in,
                              void* d_out, int out_size, void* d_ws, size_t ws_size,
                              hipStream_t stream) {
    const float* boxes = (const float*)d_in[0];
    const float* f0 = (const float*)d_in[1];
    const float* f1 = (const float*)d_in[2];
    const float* f2 = (const float*)d_in[3];
    const float* f3 = (const float*)d_in[4];
    const float* f4 = (const float*)d_in[5];
    const float* f5 = (const float*)d_in[6];
    float* out = (float*)d_out;
    int N = in_sizes[0] / 4;

    if (ws_size >= (size_t)FMT_TOTAL * sizeof(float)) {
        float* fmT = (float*)d_ws;
        transpose_fmaps<<<(FMT_TOTAL + 255) / 256, 256, 0, stream>>>(
            f0, f1, f2, f3, f4, f5, fmT);
        roialign_main<<<N, 256, 0, stream>>>(boxes, fmT, out);
    } else {
        int total4 = out_size / 4;
        roialign_fallback<<<(total4 + 255) / 256, 256, 0, stream>>>(
            boxes, f0, f1, f2, f3, f4, f5, out, total4);
    }
}